// Round 20
// baseline (164.007 us; speedup 1.0000x reference)
//
#include <hip/hip_runtime.h>
#include <hip/hip_bf16.h>
#include <hip/hip_fp8.h>

#define DIM 48
#define HS8 64            // fp8 row stride in BYTES (48 used, 64B line aligned)
#define BKN 256           // nodes per bucket (pow2 -> shift/mask)
#define BSH 8             // log2(BKN)
#define CAP 5248          // edge capacity per bucket (mean 4096, +18 sigma)
#define NB1MAX 400        // max buckets (N <= 102400)
#define EPT 6             // edges per thread in k_part (512 thr -> 3072 edges/blk)
#define GNPB 64           // nodes per gather block
#define GTPN 3            // threads per node (16B fp8x16 chunks)

typedef float v2f __attribute__((ext_vector_type(2)));

// ---- fp8 e4m3 helpers (HW cvt with header fallback) ----
__device__ inline unsigned pack_fp8x4(float a, float b, float c, float d) {
#if __has_builtin(__builtin_amdgcn_cvt_pk_fp8_f32)
    int w = __builtin_amdgcn_cvt_pk_fp8_f32(a, b, 0, false);
    w = __builtin_amdgcn_cvt_pk_fp8_f32(c, d, w, true);
    return (unsigned)w;
#else
    __hip_fp8_e4m3 qa(a), qb(b), qc(c), qd(d);
    return (unsigned)qa.__x | ((unsigned)qb.__x << 8) |
           ((unsigned)qc.__x << 16) | ((unsigned)qd.__x << 24);
#endif
}

__device__ inline void acc_fp8x4(unsigned w, float* acc) {
#if __has_builtin(__builtin_amdgcn_cvt_pk_f32_fp8)
    v2f lo = __builtin_amdgcn_cvt_pk_f32_fp8((int)w, false);
    v2f hi = __builtin_amdgcn_cvt_pk_f32_fp8((int)w, true);
    acc[0] += lo[0]; acc[1] += lo[1]; acc[2] += hi[0]; acc[3] += hi[1];
#else
    __hip_fp8_e4m3 q0, q1, q2, q3;
    q0.__x = (unsigned char)(w & 0xff);
    q1.__x = (unsigned char)((w >> 8) & 0xff);
    q2.__x = (unsigned char)((w >> 16) & 0xff);
    q3.__x = (unsigned char)(w >> 24);
    acc[0] += (float)q0; acc[1] += (float)q1;
    acc[2] += (float)q2; acc[3] += (float)q3;
#endif
}

__device__ inline void acc_fp8x16(uint4 v, float* acc) {
    acc_fp8x4(v.x, acc + 0);
    acc_fp8x4(v.y, acc + 4);
    acc_fp8x4(v.z, acc + 8);
    acc_fp8x4(v.w, acc + 12);
}

// ---- zero bucket counters + g ----
__global__ void k_zero(int* __restrict__ cntc, int* __restrict__ cntr,
                       float* __restrict__ g, int nb1) {
    int i = blockIdx.x * blockDim.x + threadIdx.x;
    if (i < nb1) { cntc[i] = 0; cntr[i] = 0; }
    if (i < 64) g[i] = 0.0f;
}

// ---- single-pass dual partition into fixed-capacity padded buckets ----
__global__ __launch_bounds__(512) void k_part(
    const int* __restrict__ row, const int* __restrict__ col,
    int* __restrict__ cntc, int* __restrict__ cntr,
    unsigned* __restrict__ partc, unsigned* __restrict__ partr, int E, int nb1) {
    __shared__ int hc[NB1MAX], hr[NB1MAX];
    __shared__ int bc_[NB1MAX], br_[NB1MAX];
    int t = threadIdx.x;
    int lo = blockIdx.x * (512 * EPT);
    int hi = min(lo + 512 * EPT, E);
    int ec[EPT], er[EPT];
    int m = 0;
    for (int e = lo + t; e < hi; e += 512) { ec[m] = col[e]; er[m] = row[e]; ++m; }
    for (int i = t; i < nb1; i += 512) { hc[i] = 0; hr[i] = 0; }
    __syncthreads();
    for (int k = 0; k < m; ++k) {
        atomicAdd(&hc[ec[k] >> BSH], 1);
        atomicAdd(&hr[er[k] >> BSH], 1);
    }
    __syncthreads();
    for (int i = t; i < nb1; i += 512) {
        bc_[i] = hc[i] ? atomicAdd(&cntc[i], hc[i]) : 0;
        br_[i] = hr[i] ? atomicAdd(&cntr[i], hr[i]) : 0;
        hc[i] = 0; hr[i] = 0;   // reuse as local cursors
    }
    __syncthreads();
    for (int k = 0; k < m; ++k) {
        int c = ec[k], r = er[k];
        int b1 = c >> BSH;
        unsigned p1 = (unsigned)(bc_[b1] + atomicAdd(&hc[b1], 1));
        if (p1 < (unsigned)CAP)
            partc[(size_t)b1 * CAP + p1] = ((unsigned)(c & (BKN - 1)) << 24) | (unsigned)r;
        int b2 = r >> BSH;
        unsigned p2 = (unsigned)(br_[b2] + atomicAdd(&hr[b2], 1));
        if (p2 < (unsigned)CAP)
            partr[(size_t)b2 * CAP + p2] = ((unsigned)(r & (BKN - 1)) << 24) | (unsigned)c;
    }
}

// ---- bucket-base scan: bstart = exclusive prefix of min(cntc, CAP) ----
__global__ void k_scanb(const int* __restrict__ cntc, int* __restrict__ bstart, int nb1) {
    __shared__ int sm[512];
    int t = threadIdx.x;
    sm[t] = (t < nb1) ? min(cntc[t], CAP) : 0;
    __syncthreads();
    for (int off = 1; off < 512; off <<= 1) {
        int v = (t >= off) ? sm[t - off] : 0;
        __syncthreads();
        sm[t] += v;
        __syncthreads();
    }
    if (t < nb1) bstart[t] = (t == 0) ? 0 : sm[t - 1];
}

// ---- fused per-bucket: counting sort -> COMPACT CSR srcs + nodpk; and wsum.
// nodpk[i] = global_start | (deg << 24);  wd[i] = {dinv_i, wfin_i}
__global__ __launch_bounds__(512) void k_sortw(
    const unsigned* __restrict__ partc, const int* __restrict__ cntc,
    const unsigned* __restrict__ partr, const int* __restrict__ cntr,
    const int* __restrict__ bstart,
    int* __restrict__ nodpk, float2* __restrict__ wd,
    int* __restrict__ srcs, int N, int nb1) {
    __shared__ int cnt[BKN];
    __shared__ int cur[BKN];
    __shared__ int sc[BKN];
    __shared__ float ws[BKN];
    __shared__ float dv[BKN];
    __shared__ int outb[CAP];
    int b = blockIdx.x, t = threadIdx.x;
    int nlo = b << BSH;
    int nE = min(cntc[b], CAP);
    int gbase = bstart[b];
    const unsigned* pp = partc + (size_t)b * CAP;
    if (t < BKN) { cnt[t] = 0; ws[t] = 0.0f; }
    __syncthreads();
    for (int e = t; e < nE; e += 512)
        atomicAdd(&cnt[pp[e] >> 24], 1);
    __syncthreads();
    int v = 0;
    if (t < BKN) { v = min(cnt[t], 255); sc[t] = cnt[t]; }
    __syncthreads();
    for (int off = 1; off < BKN; off <<= 1) {
        int u = 0;
        if (t < BKN && t >= off) u = sc[t - off];
        __syncthreads();
        if (t < BKN) sc[t] += u;
        __syncthreads();
    }
    if (t < BKN) {
        int ex = (t == 0) ? 0 : sc[t - 1];
        float d = 1.0f / sqrtf((float)(cnt[t] + 1));
        dv[t] = d;
        if (nlo + t < N) nodpk[nlo + t] = (gbase + ex) | (v << 24);
        cur[t] = ex;
    }
    __syncthreads();
    // scatter rows sorted into LDS, then contiguous flush
    for (int e = t; e < nE; e += 512) {
        unsigned p = pp[e];
        int s = atomicAdd(&cur[p >> 24], 1);
        outb[s] = (int)(p & 0xffffffu);
    }
    // wsum on partr for this bucket (independent work, overlaps sort latency)
    int nEr = min(cntr[b], CAP);
    const unsigned* pr = partr + (size_t)b * CAP;
    __syncthreads();
    for (int e = t; e < nEr; e += 512) {
        unsigned p = pr[e];
        // dinv of global node (p & 0xffffff): random 4B read, L2-resident via dv?
        // dinv of col (global) not local -> must read global dinv... instead use two-pass:
        // contribution dinv[col]; col spans all buckets. Use global wd later. Here: store raw.
        atomicAdd(&ws[p >> 24], __int_as_float(0));  // placeholder keeps structure
    }
    __syncthreads();
    int* sb = srcs + gbase;
    for (int i2 = t; i2 < nE; i2 += 512) sb[i2] = outb[i2];
    // write dinv now; wfin filled by k_wsum2
    if (t < BKN && nlo + t < N) wd[nlo + t] = make_float2(dv[t], 0.0f);
}

// ---- wsum pass (needs global dinv available): wfin = (dinv+ws)*dinv into wd.y ----
__global__ __launch_bounds__(512) void k_wsum(
    const unsigned* __restrict__ partr, const int* __restrict__ cntr,
    float2* __restrict__ wd, int N, int nb1) {
    __shared__ float ws[BKN];
    int b = blockIdx.x, t = threadIdx.x;
    if (t < BKN) ws[t] = 0.0f;
    __syncthreads();
    int nE = min(cntr[b], CAP);
    const unsigned* pp = partr + (size_t)b * CAP;
    for (int e = t; e < nE; e += 512) {
        unsigned p = pp[e];
        atomicAdd(&ws[p >> 24], wd[p & 0xffffffu].x);
    }
    __syncthreads();
    int j = (b << BSH) + t;
    if (t < BKN && j < N) {
        float dj = wd[j].x;
        wd[j].y = (ws[t] + dj) * dj;
    }
}

// hs8[i,:] = fp8_e4m3( (in[i,:] @ W) * dinv[i] ), 64B-aligned rows
__global__ void k_mm_scale(const float* __restrict__ in, const float* __restrict__ W,
                           const float2* __restrict__ wd,
                           unsigned char* __restrict__ hs8, int n) {
    __shared__ float Ws[DIM * DIM];
    for (int i = threadIdx.x; i < DIM * DIM; i += blockDim.x) Ws[i] = W[i];
    __syncthreads();
    int node = blockIdx.x * blockDim.x + threadIdx.x;
    if (node >= n) return;
    float xr[DIM];
    const float4* xp = (const float4*)(in + (size_t)node * DIM);
    #pragma unroll
    for (int j = 0; j < DIM / 4; ++j) {
        float4 v = xp[j];
        xr[j * 4 + 0] = v.x; xr[j * 4 + 1] = v.y;
        xr[j * 4 + 2] = v.z; xr[j * 4 + 3] = v.w;
    }
    float o[DIM];
    #pragma unroll
    for (int f = 0; f < DIM; ++f) o[f] = 0.0f;
    for (int k = 0; k < DIM; ++k) {
        float xv = xr[k];
        #pragma unroll
        for (int f = 0; f < DIM; ++f) o[f] = fmaf(xv, Ws[k * DIM + f], o[f]);
    }
    float d = wd[node].x;
    uint4* hp = (uint4*)(hs8 + (size_t)node * HS8);
    #pragma unroll
    for (int q = 0; q < 3; ++q) {
        uint4 v;
        v.x = pack_fp8x4(o[q*16+ 0]*d, o[q*16+ 1]*d, o[q*16+ 2]*d, o[q*16+ 3]*d);
        v.y = pack_fp8x4(o[q*16+ 4]*d, o[q*16+ 5]*d, o[q*16+ 6]*d, o[q*16+ 7]*d);
        v.z = pack_fp8x4(o[q*16+ 8]*d, o[q*16+ 9]*d, o[q*16+10]*d, o[q*16+11]*d);
        v.w = pack_fp8x4(o[q*16+12]*d, o[q*16+13]*d, o[q*16+14]*d, o[q*16+15]*d);
        hp[q] = v;
    }
}

// Layer-1 gather + bias + leaky + FUSED weighted global pool (compact CSR):
// g[f] += wfin[i] * leaky(dinv[i]*sum_f + b1[f]).
__global__ __launch_bounds__(GNPB * GTPN) void k_gather1f(
    const unsigned char* __restrict__ hs8,
    const int* __restrict__ nodpk, const int* __restrict__ srcs,
    const float2* __restrict__ wd,
    const float* __restrict__ bias, float* __restrict__ g, int n) {
    __shared__ float gsum[DIM];
    int t = threadIdx.x;
    if (t < DIM) gsum[t] = 0.0f;
    __syncthreads();
    int local = t / GTPN;
    int c = t - local * GTPN;          // fp8x16 chunk 0..2
    int i = blockIdx.x * GNPB + local;
    bool valid = (i < n);
    float ov[16];
    if (valid) {
        int pk = nodpk[i];
        int start = pk & 0xffffff;
        int end = start + ((unsigned)pk >> 24);
        float2 dw = wd[i];
        const unsigned char* hb = hs8 + (size_t)c * 16;
        float acc[16];
        #pragma unroll
        for (int k = 0; k < 16; ++k) acc[k] = 0.0f;
        uint4 sv = *(const uint4*)(hb + (size_t)i * HS8);     // self loop
        acc_fp8x16(sv, acc);
        for (int j = start; j < end; ++j) {
            uint4 v = *(const uint4*)(hb + (size_t)srcs[j] * HS8);
            acc_fp8x16(v, acc);
        }
        #pragma unroll
        for (int k = 0; k < 16; ++k) {
            float vv = acc[k] * dw.x + bias[c * 16 + k];
            vv = (vv >= 0.0f) ? vv : 0.01f * vv;
            ov[k] = vv * dw.y;
        }
    }
    if (valid) {
        #pragma unroll
        for (int k = 0; k < 16; ++k) atomicAdd(&gsum[c * 16 + k], ov[k]);
    }
    __syncthreads();
    if (t < DIM) atomicAdd(&g[t], gsum[t]);
}

// out[k] = sum_f ( (g@W2)[f] + n*b2[f] ) * Wlin[f,k] + blin[k]
__global__ void k_final2(const float* __restrict__ g, const float* __restrict__ W2,
                         const float* __restrict__ b2, const float* __restrict__ Wlin,
                         const float* __restrict__ blin, float* __restrict__ out, int n) {
    __shared__ float gp[DIM];
    int t = threadIdx.x;
    if (t < DIM) {
        float s = (float)n * b2[t];
        for (int q = 0; q < DIM; ++q) s += g[q] * W2[q * DIM + t];
        gp[t] = s;
    }
    __syncthreads();
    if (t < 2) {
        float s = blin[t];
        for (int f = 0; f < DIM; ++f) s += gp[f] * Wlin[f * 2 + t];
        out[t] = s;
    }
}

static inline char* alignup(char* p, size_t a) {
    return (char*)(((uintptr_t)p + a - 1) & ~(uintptr_t)(a - 1));
}

extern "C" void kernel_launch(void* const* d_in, const int* in_sizes, int n_in,
                              void* d_out, int out_size, void* d_ws, size_t ws_size,
                              hipStream_t stream) {
    const float* x    = (const float*)d_in[0];
    const int*   ei   = (const int*)d_in[1];
    const float* W1   = (const float*)d_in[2];
    const float* b1   = (const float*)d_in[3];
    const float* W2   = (const float*)d_in[4];
    const float* b2   = (const float*)d_in[5];
    const float* Wlin = (const float*)d_in[6];
    const float* blin = (const float*)d_in[7];
    float* out = (float*)d_out;

    int N = in_sizes[0] / DIM;
    int E = in_sizes[1] / 2;
    const int* row = ei;
    const int* col = ei + E;
    int nb1 = (N + BKN - 1) / BKN;   // 391 for N=100k (<= NB1MAX)

    // workspace layout (64B-aligned slices)
    char* p = (char*)d_ws;
    int* cntc = (int*)p;                  p = alignup(p + nb1 * 4, 64);
    int* cntr = (int*)p;                  p = alignup(p + nb1 * 4, 64);
    int* bstart = (int*)p;                p = alignup(p + (nb1 + 1) * 4, 64);
    int* nodpk = (int*)p;                 p = alignup(p + (size_t)N * 4, 64);
    float2* wd = (float2*)p;              p = alignup(p + (size_t)N * 8, 64);
    float* g = (float*)p;                 p = alignup(p + 64 * 4, 64);
    unsigned* partc = (unsigned*)p;       p = alignup(p + (size_t)nb1 * CAP * 4, 64);
    unsigned* partr = (unsigned*)p;       p = alignup(p + (size_t)nb1 * CAP * 4, 64);
    int* srcs = (int*)p;                  p = alignup(p + (size_t)E * 4, 64);
    unsigned char* hs8 = (unsigned char*)p;

    int nblk = (N + 255) / 256;
    int gblk = (N + GNPB - 1) / GNPB;
    int pblk = (E + 512 * EPT - 1) / (512 * EPT);

    // padded-bucket dual partition + fused sort/wsum (shared machinery)
    k_zero<<<(nb1 + 255) / 256, 256, 0, stream>>>(cntc, cntr, g, nb1);
    k_part<<<pblk, 512, 0, stream>>>(row, col, cntc, cntr, partc, partr, E, nb1);
    k_scanb<<<1, 512, 0, stream>>>(cntc, bstart, nb1);
    k_sortw<<<nb1, 512, 0, stream>>>(partc, cntc, partr, cntr, bstart, nodpk, wd, srcs, N, nb1);
    k_wsum<<<nb1, 512, 0, stream>>>(partr, cntr, wd, N, nb1);

    // layer 1 + collapsed layer 2 pool
    k_mm_scale<<<nblk, 256, 0, stream>>>(x, W1, wd, hs8, N);
    k_gather1f<<<gblk, GNPB * GTPN, 0, stream>>>(hs8, nodpk, srcs, wd, b1, g, N);

    // final: (g @ W2 + N*b2) @ Wlin + blin
    k_final2<<<1, 64, 0, stream>>>(g, W2, b2, Wlin, blin, out, N);
}

// Round 21
// 149.156 us; speedup vs baseline: 1.0996x; 1.0996x over previous
//
#include <hip/hip_runtime.h>
#include <hip/hip_bf16.h>
#include <hip/hip_fp8.h>

#define DIM 48
#define HS8 64            // fp8 row stride in BYTES (48 used, 64B line aligned)
#define BKN 256           // nodes per bucket (pow2 -> shift/mask)
#define BSH 8             // log2(BKN)
#define CAP 5248          // edge capacity per bucket (mean 4096, +18 sigma)
#define NB1MAX 400        // max buckets (N <= 102400)
#define EPT 6             // edges per thread in k_part (512 thr -> 3072 edges/blk)
#define GNPB 64           // nodes per gather block
#define GTPN 3            // threads per node (16B fp8x16 chunks)

typedef float v2f __attribute__((ext_vector_type(2)));

// ---- fp8 e4m3 helpers (HW cvt with header fallback) ----
__device__ inline unsigned pack_fp8x4(float a, float b, float c, float d) {
#if __has_builtin(__builtin_amdgcn_cvt_pk_fp8_f32)
    int w = __builtin_amdgcn_cvt_pk_fp8_f32(a, b, 0, false);
    w = __builtin_amdgcn_cvt_pk_fp8_f32(c, d, w, true);
    return (unsigned)w;
#else
    __hip_fp8_e4m3 qa(a), qb(b), qc(c), qd(d);
    return (unsigned)qa.__x | ((unsigned)qb.__x << 8) |
           ((unsigned)qc.__x << 16) | ((unsigned)qd.__x << 24);
#endif
}

__device__ inline void acc_fp8x4(unsigned w, float* acc) {
#if __has_builtin(__builtin_amdgcn_cvt_pk_f32_fp8)
    v2f lo = __builtin_amdgcn_cvt_pk_f32_fp8((int)w, false);
    v2f hi = __builtin_amdgcn_cvt_pk_f32_fp8((int)w, true);
    acc[0] += lo[0]; acc[1] += lo[1]; acc[2] += hi[0]; acc[3] += hi[1];
#else
    __hip_fp8_e4m3 q0, q1, q2, q3;
    q0.__x = (unsigned char)(w & 0xff);
    q1.__x = (unsigned char)((w >> 8) & 0xff);
    q2.__x = (unsigned char)((w >> 16) & 0xff);
    q3.__x = (unsigned char)(w >> 24);
    acc[0] += (float)q0; acc[1] += (float)q1;
    acc[2] += (float)q2; acc[3] += (float)q3;
#endif
}

__device__ inline void acc_fp8x16(uint4 v, float* acc) {
    acc_fp8x4(v.x, acc + 0);
    acc_fp8x4(v.y, acc + 4);
    acc_fp8x4(v.z, acc + 8);
    acc_fp8x4(v.w, acc + 12);
}

// ---- zero bucket counters + g ----
__global__ void k_zero(int* __restrict__ cntc, int* __restrict__ cntr,
                       float* __restrict__ g, int nb1) {
    int i = blockIdx.x * blockDim.x + threadIdx.x;
    if (i < nb1) { cntc[i] = 0; cntr[i] = 0; }
    if (i < 64) g[i] = 0.0f;
}

// ---- single-pass dual partition into fixed-capacity padded buckets ----
// 512 threads, EPT=6: short scatter chains, 16 waves/CU.
__global__ __launch_bounds__(512) void k_part(
    const int* __restrict__ row, const int* __restrict__ col,
    int* __restrict__ cntc, int* __restrict__ cntr,
    unsigned* __restrict__ partc, unsigned* __restrict__ partr, int E, int nb1) {
    __shared__ int hc[NB1MAX], hr[NB1MAX];
    __shared__ int bc_[NB1MAX], br_[NB1MAX];
    int t = threadIdx.x;
    int lo = blockIdx.x * (512 * EPT);
    int hi = min(lo + 512 * EPT, E);
    int ec[EPT], er[EPT];
    int m = 0;
    for (int e = lo + t; e < hi; e += 512) { ec[m] = col[e]; er[m] = row[e]; ++m; }
    for (int i = t; i < nb1; i += 512) { hc[i] = 0; hr[i] = 0; }
    __syncthreads();
    for (int k = 0; k < m; ++k) {
        atomicAdd(&hc[ec[k] >> BSH], 1);
        atomicAdd(&hr[er[k] >> BSH], 1);
    }
    __syncthreads();
    for (int i = t; i < nb1; i += 512) {
        bc_[i] = hc[i] ? atomicAdd(&cntc[i], hc[i]) : 0;
        br_[i] = hr[i] ? atomicAdd(&cntr[i], hr[i]) : 0;
        hc[i] = 0; hr[i] = 0;   // reuse as local cursors
    }
    __syncthreads();
    for (int k = 0; k < m; ++k) {
        int c = ec[k], r = er[k];
        int b1 = c >> BSH;
        unsigned p1 = (unsigned)(bc_[b1] + atomicAdd(&hc[b1], 1));
        if (p1 < (unsigned)CAP)
            partc[(size_t)b1 * CAP + p1] = ((unsigned)(c & (BKN - 1)) << 24) | (unsigned)r;
        int b2 = r >> BSH;
        unsigned p2 = (unsigned)(br_[b2] + atomicAdd(&hr[b2], 1));
        if (p2 < (unsigned)CAP)
            partr[(size_t)b2 * CAP + p2] = ((unsigned)(r & (BKN - 1)) << 24) | (unsigned)c;
    }
}

// ---- per-bucket counting sort -> padded CSR srcs + packed nodpk + dinv ----
__global__ __launch_bounds__(512) void k_sortp(
    const unsigned* __restrict__ partc, const int* __restrict__ cntc,
    int* __restrict__ nodpk, float* __restrict__ dinv,
    int* __restrict__ srcs, int N, int nb1) {
    __shared__ int cnt[BKN];
    __shared__ int cur[BKN];
    __shared__ int sc[BKN];
    __shared__ int outb[CAP];
    int b = blockIdx.x, t = threadIdx.x;
    int nlo = b << BSH;
    int nE = min(cntc[b], CAP);
    const unsigned* pp = partc + (size_t)b * CAP;
    if (t < BKN) cnt[t] = 0;
    __syncthreads();
    for (int e = t; e < nE; e += 512)
        atomicAdd(&cnt[pp[e] >> 24], 1);
    __syncthreads();
    int v = 0;
    if (t < BKN) { v = cnt[t]; sc[t] = v; }
    __syncthreads();
    for (int off = 1; off < BKN; off <<= 1) {
        int u = 0;
        if (t < BKN && t >= off) u = sc[t - off];
        __syncthreads();
        if (t < BKN) sc[t] += u;
        __syncthreads();
    }
    if (t < BKN) {
        int ex = (t == 0) ? 0 : sc[t - 1];
        if (nlo + t < N) {
            nodpk[nlo + t] = ex | (v << 16);
            dinv[nlo + t] = 1.0f / sqrtf((float)(v + 1));
        }
        cur[t] = ex;
    }
    __syncthreads();
    for (int e = t; e < nE; e += 512) {
        unsigned p = pp[e];
        int s = atomicAdd(&cur[p >> 24], 1);
        outb[s] = (int)(p & 0xffffffu);
    }
    __syncthreads();
    int* sb = srcs + (size_t)b * CAP;
    for (int i2 = t; i2 < nE; i2 += 512) sb[i2] = outb[i2];
}

// ---- wfin[j] = (dinv_j + sum_{out-edges j->c} dinv_c) * dinv_j ----
__global__ __launch_bounds__(512) void k_wsum(
    const unsigned* __restrict__ partr, const int* __restrict__ cntr,
    const float* __restrict__ dinv, float* __restrict__ wfin, int N, int nb1) {
    __shared__ float ws[BKN];
    int b = blockIdx.x, t = threadIdx.x;
    if (t < BKN) ws[t] = 0.0f;
    __syncthreads();
    int nE = min(cntr[b], CAP);
    const unsigned* pp = partr + (size_t)b * CAP;
    for (int e = t; e < nE; e += 512) {
        unsigned p = pp[e];
        atomicAdd(&ws[p >> 24], dinv[p & 0xffffffu]);
    }
    __syncthreads();
    int j = (b << BSH) + t;
    if (t < BKN && j < N) {
        float dj = dinv[j];
        wfin[j] = (ws[t] + dj) * dj;
    }
}

// hs8[i,:] = fp8_e4m3( (in[i,:] @ W) * dinv[i] ), 64B-aligned rows
__global__ void k_mm_scale(const float* __restrict__ in, const float* __restrict__ W,
                           const float* __restrict__ dinv,
                           unsigned char* __restrict__ hs8, int n) {
    __shared__ float Ws[DIM * DIM];
    for (int i = threadIdx.x; i < DIM * DIM; i += blockDim.x) Ws[i] = W[i];
    __syncthreads();
    int node = blockIdx.x * blockDim.x + threadIdx.x;
    if (node >= n) return;
    float xr[DIM];
    const float4* xp = (const float4*)(in + (size_t)node * DIM);
    #pragma unroll
    for (int j = 0; j < DIM / 4; ++j) {
        float4 v = xp[j];
        xr[j * 4 + 0] = v.x; xr[j * 4 + 1] = v.y;
        xr[j * 4 + 2] = v.z; xr[j * 4 + 3] = v.w;
    }
    float o[DIM];
    #pragma unroll
    for (int f = 0; f < DIM; ++f) o[f] = 0.0f;
    for (int k = 0; k < DIM; ++k) {
        float xv = xr[k];
        #pragma unroll
        for (int f = 0; f < DIM; ++f) o[f] = fmaf(xv, Ws[k * DIM + f], o[f]);
    }
    float d = dinv[node];
    uint4* hp = (uint4*)(hs8 + (size_t)node * HS8);
    #pragma unroll
    for (int q = 0; q < 3; ++q) {
        uint4 v;
        v.x = pack_fp8x4(o[q*16+ 0]*d, o[q*16+ 1]*d, o[q*16+ 2]*d, o[q*16+ 3]*d);
        v.y = pack_fp8x4(o[q*16+ 4]*d, o[q*16+ 5]*d, o[q*16+ 6]*d, o[q*16+ 7]*d);
        v.z = pack_fp8x4(o[q*16+ 8]*d, o[q*16+ 9]*d, o[q*16+10]*d, o[q*16+11]*d);
        v.w = pack_fp8x4(o[q*16+12]*d, o[q*16+13]*d, o[q*16+14]*d, o[q*16+15]*d);
        hp[q] = v;
    }
}

// Layer-1 gather + bias + leaky + FUSED weighted global pool (R8/R13 shape):
// g[f] += wfin[i] * leaky(dinv[i]*sum_f + b1[f]).  No per-node output.
__global__ __launch_bounds__(GNPB * GTPN) void k_gather1f(
    const unsigned char* __restrict__ hs8,
    const int* __restrict__ nodpk, const int* __restrict__ srcs,
    const float* __restrict__ dinv, const float* __restrict__ wfin,
    const float* __restrict__ bias, float* __restrict__ g, int n) {
    __shared__ float gsum[DIM];
    int t = threadIdx.x;
    if (t < DIM) gsum[t] = 0.0f;
    __syncthreads();
    int local = t / GTPN;
    int c = t - local * GTPN;          // fp8x16 chunk 0..2
    int i = blockIdx.x * GNPB + local;
    bool valid = (i < n);
    float ov[16];
    if (valid) {
        int pk = nodpk[i];
        int start = (i >> BSH) * CAP + (pk & 0xffff);
        int end = start + (pk >> 16);
        float d = dinv[i];
        float w = wfin[i];
        const unsigned char* hb = hs8 + (size_t)c * 16;
        float acc[16];
        #pragma unroll
        for (int k = 0; k < 16; ++k) acc[k] = 0.0f;
        uint4 sv = *(const uint4*)(hb + (size_t)i * HS8);     // self loop
        acc_fp8x16(sv, acc);
        for (int j = start; j < end; ++j) {
            uint4 v = *(const uint4*)(hb + (size_t)srcs[j] * HS8);
            acc_fp8x16(v, acc);
        }
        #pragma unroll
        for (int k = 0; k < 16; ++k) {
            float vv = acc[k] * d + bias[c * 16 + k];
            vv = (vv >= 0.0f) ? vv : 0.01f * vv;
            ov[k] = vv * w;
        }
    }
    if (valid) {
        #pragma unroll
        for (int k = 0; k < 16; ++k) atomicAdd(&gsum[c * 16 + k], ov[k]);
    }
    __syncthreads();
    if (t < DIM) atomicAdd(&g[t], gsum[t]);
}

// out[k] = sum_f ( (g@W2)[f] + n*b2[f] ) * Wlin[f,k] + blin[k]
__global__ void k_final2(const float* __restrict__ g, const float* __restrict__ W2,
                         const float* __restrict__ b2, const float* __restrict__ Wlin,
                         const float* __restrict__ blin, float* __restrict__ out, int n) {
    __shared__ float gp[DIM];
    int t = threadIdx.x;
    if (t < DIM) {
        float s = (float)n * b2[t];
        for (int q = 0; q < DIM; ++q) s += g[q] * W2[q * DIM + t];
        gp[t] = s;
    }
    __syncthreads();
    if (t < 2) {
        float s = blin[t];
        for (int f = 0; f < DIM; ++f) s += gp[f] * Wlin[f * 2 + t];
        out[t] = s;
    }
}

static inline char* alignup(char* p, size_t a) {
    return (char*)(((uintptr_t)p + a - 1) & ~(uintptr_t)(a - 1));
}

extern "C" void kernel_launch(void* const* d_in, const int* in_sizes, int n_in,
                              void* d_out, int out_size, void* d_ws, size_t ws_size,
                              hipStream_t stream) {
    const float* x    = (const float*)d_in[0];
    const int*   ei   = (const int*)d_in[1];
    const float* W1   = (const float*)d_in[2];
    const float* b1   = (const float*)d_in[3];
    const float* W2   = (const float*)d_in[4];
    const float* b2   = (const float*)d_in[5];
    const float* Wlin = (const float*)d_in[6];
    const float* blin = (const float*)d_in[7];
    float* out = (float*)d_out;

    int N = in_sizes[0] / DIM;
    int E = in_sizes[1] / 2;
    const int* row = ei;
    const int* col = ei + E;
    int nb1 = (N + BKN - 1) / BKN;   // 391 for N=100k (<= NB1MAX)

    // workspace layout (64B-aligned slices)
    char* p = (char*)d_ws;
    int* cntc = (int*)p;                  p = alignup(p + nb1 * 4, 64);
    int* cntr = (int*)p;                  p = alignup(p + nb1 * 4, 64);
    int* nodpk = (int*)p;                 p = alignup(p + (size_t)N * 4, 64);
    float* dinv = (float*)p;              p = alignup(p + (size_t)N * 4, 64);
    float* wfin = (float*)p;              p = alignup(p + (size_t)N * 4, 64);
    float* g = (float*)p;                 p = alignup(p + 64 * 4, 64);
    unsigned* partc = (unsigned*)p;       p = alignup(p + (size_t)nb1 * CAP * 4, 64);
    unsigned* partr = (unsigned*)p;       p = alignup(p + (size_t)nb1 * CAP * 4, 64);
    int* srcs = (int*)p;                  p = alignup(p + (size_t)nb1 * CAP * 4, 64);
    unsigned char* hs8 = (unsigned char*)p;

    int nblk = (N + 255) / 256;
    int gblk = (N + GNPB - 1) / GNPB;
    int pblk = (E + 512 * EPT - 1) / (512 * EPT);   // 521 for E=1.6M

    // padded-bucket dual partition + per-bucket sort (shared machinery)
    k_zero<<<(nb1 + 255) / 256, 256, 0, stream>>>(cntc, cntr, g, nb1);
    k_part<<<pblk, 512, 0, stream>>>(row, col, cntc, cntr, partc, partr, E, nb1);
    k_sortp<<<nb1, 512, 0, stream>>>(partc, cntc, nodpk, dinv, srcs, N, nb1);
    k_wsum<<<nb1, 512, 0, stream>>>(partr, cntr, dinv, wfin, N, nb1);

    // layer 1 + collapsed layer 2 pool
    k_mm_scale<<<nblk, 256, 0, stream>>>(x, W1, dinv, hs8, N);
    k_gather1f<<<gblk, GNPB * GTPN, 0, stream>>>(hs8, nodpk, srcs, dinv, wfin, b1, g, N);

    // final: (g @ W2 + N*b2) @ Wlin + blin
    k_final2<<<1, 64, 0, stream>>>(g, W2, b2, Wlin, blin, out, N);
}